// Round 2
// baseline (13.893 us; speedup 1.0000x reference)
//
#include <hip/hip_runtime.h>
#include <stdint.h>

#define M_MACH 50
#define N_JOBS 100
#define NFEAT 5400        // 50*4 + 100*2 + 50*100
#define A_DIM 32
#define C_DIM 1000
#define INIT_T 16
#define WAVES_PER_BLOCK 8 // 512 threads

// One wave per clause. Chunk 0 (features 0..63, all machine-time bits) is
// computed in-register; ta bytes for BOTH planes are loaded up front so the
// global loads don't depend on the feature bits. Early-exit on first
// violation; statistically ~0 clauses survive chunk 0 with this data, but the
// full on-the-fly scan keeps it correct for any input.
__global__ __launch_bounds__(512) void fused_clause_kernel(
    const float* __restrict__ state,
    const int8_t* __restrict__ ta,
    const int8_t* __restrict__ sign,
    float* __restrict__ out) {
    const int lane = threadIdx.x & 63;
    const int wid  = threadIdx.x >> 6;
    const int q    = blockIdx.x * WAVES_PER_BLOCK + wid;   // 0..31999
    const int8_t* base = ta + (size_t)q * (2 * NFEAT);

    // Issue ta chunk-0 loads immediately (independent of feature bits).
    const int in0 = base[lane];          // include plane, f = lane
    const int ex0 = base[NFEAT + lane];  // exclude plane, f = lane

    // Wave-wide max over state[0..49] (overlaps the ta load latency).
    const float v0 = (lane < M_MACH) ? state[lane] : -1.0f;
    float mx = v0;
    #pragma unroll
    for (int off = 1; off < 64; off <<= 1)
        mx = fmaxf(mx, __shfl_xor(mx, off, 64));

    // Chunk-0 feature bit: f = lane -> machine i = lane>>2, bit k = lane&3.
    const float s_i = __shfl(v0, lane >> 2, 64);
    const int norm = (mx > 0.0f) ? (int)((s_i / mx) * 15.0f) : 0;
    const int bit  = (norm >> (lane & 3)) & 1;

    const bool v = ((bit ? ex0 : in0) > INIT_T);
    if (__any(v)) return;                         // violated: contributes 0

    // Rare path: full scan, computing feature bits on the fly.
    for (int f0 = 64; f0 < NFEAT; f0 += 64) {
        const int f = f0 + lane;
        bool vv = false;
        if (f < NFEAT) {
            int b;
            if (f < M_MACH * 4) {                       // machine-time bits
                const int i = f >> 2;
                const int n2 = (mx > 0.0f) ? (int)((state[i] / mx) * 15.0f) : 0;
                b = (n2 >> (f & 3)) & 1;
            } else if (f < M_MACH * 4 + N_JOBS * 2) {   // job-status bits
                const int rel = f - M_MACH * 4;
                const int j = rel >> 1;
                int st = (int)(state[M_MACH + j] * 3.0f);
                if (st > 3) st = 3;
                b = (st >> (rel & 1)) & 1;
            } else {                                    // op-status bits
                b = (int)state[M_MACH + N_JOBS + (f - (M_MACH*4 + N_JOBS*2))];
            }
            vv = ((b ? base[NFEAT + f] : base[f]) > INIT_T);
        }
        if (__any(vv)) return;
    }

    if (lane == 0) atomicAdd(&out[q / C_DIM], (float)sign[q]);
}

extern "C" void kernel_launch(void* const* d_in, const int* in_sizes, int n_in,
                              void* d_out, int out_size, void* d_ws, size_t ws_size,
                              hipStream_t stream) {
    const float*  state = (const float*)d_in[0];
    const int8_t* ta    = (const int8_t*)d_in[1];
    const int8_t* sign  = (const int8_t*)d_in[2];
    float* out = (float*)d_out;

    // Harness poisons d_out once and never re-poisons between replays; the
    // atomics below need zeros every call.
    hipMemsetAsync(out, 0, out_size * sizeof(float), stream);

    // 4000 blocks x 8 waves = 32000 waves, exactly one clause each.
    fused_clause_kernel<<<4000, 512, 0, stream>>>(state, ta, sign, out);
}